// Round 23
// baseline (128.035 us; speedup 1.0000x reference)
//
#include <hip/hip_runtime.h>

typedef __bf16 bf16;
typedef __bf16 bf16x8 __attribute__((ext_vector_type(8)));
typedef __bf16 bf16x4 __attribute__((ext_vector_type(4)));
typedef float f32x4 __attribute__((ext_vector_type(4)));
typedef float f32x16 __attribute__((ext_vector_type(16)));
typedef float fx2 __attribute__((ext_vector_type(2)));

#define DEV static __device__ __forceinline__

constexpr int BB = 2, SS = 2048, DM = 1024, NH = 16, HD = 64;
constexpr int MTOT = BB * SS;  // 4096
constexpr float LOG2E = 1.4426950408889634f;

// ---- workspace layout (bytes) ----
constexpr size_t OFF_XB   = 0;                                  // bf16 [4096][1024]
constexpr size_t OFF_WQKV = OFF_XB   + (size_t)MTOT * DM * 2;   // bf16 [3072][1024]
constexpr size_t OFF_WO   = OFF_WQKV + (size_t)3 * DM * DM * 2; // bf16 [1024][1024]
constexpr size_t OFF_TAB  = OFF_WO   + (size_t)DM * DM * 2;     // fx2  [2048][32]
constexpr size_t OFF_Q    = OFF_TAB  + (size_t)SS * (HD/2) * 8; // bf16 (B,H,S,d)
constexpr size_t OFF_KF   = OFF_Q    + (size_t)MTOT * DM * 2;   // bf16 pre-fragmented K
constexpr size_t OFF_VF   = OFF_KF   + (size_t)MTOT * DM * 2;   // bf16 pre-fragmented V
constexpr size_t OFF_AO   = OFF_VF   + (size_t)MTOT * DM * 2;   // bf16 [4096][1024]

typedef const __attribute__((address_space(1))) void gas_void;
typedef __attribute__((address_space(3))) void las_void;

DEV void gload16(const bf16* g, bf16* l) {
  __builtin_amdgcn_global_load_lds((gas_void*)g, (las_void*)l, 16, 0, 0);
}

DEV f32x4 mfma16(bf16x8 a, bf16x8 b, f32x4 c) {
  return __builtin_amdgcn_mfma_f32_16x16x32_bf16(a, b, c, 0, 0, 0);
}

DEV f32x16 mfma32(bf16x8 a, bf16x8 b, f32x16 c) {
  return __builtin_amdgcn_mfma_f32_32x32x16_bf16(a, b, c, 0, 0, 0);
}

DEV unsigned pack2(float a, float b) {
  union { bf16 h[2]; unsigned u; } cv;
  cv.h[0] = (bf16)a; cv.h[1] = (bf16)b;
  return cv.u;
}

// ---------------- prep: fp32 -> bf16 casts + RoPE table ----------------
__global__ void prep_kernel(const float* __restrict__ x, const float* __restrict__ wq,
    const float* __restrict__ wk, const float* __restrict__ wv, const float* __restrict__ wo,
    const int* __restrict__ pos, bf16* __restrict__ xb, bf16* __restrict__ wqkv,
    bf16* __restrict__ wob, fx2* __restrict__ tab) {
  const int NX4 = MTOT * DM / 4;     // 1048576
  const int NW4 = DM * DM / 4;       // 262144 = 2^18
  const int TOTC = NX4 + 4 * NW4;    // 2097152
  const int NTAB = SS * (HD / 2);    // 65536
  const int total = TOTC + NTAB;
  for (int i = blockIdx.x * blockDim.x + threadIdx.x; i < total; i += gridDim.x * blockDim.x) {
    if (i < TOTC) {
      const float* src; bf16* dst; int off;
      if (i < NX4) { src = x; dst = xb; off = i; }
      else {
        int i2 = i - NX4; int which = i2 >> 18; off = i2 & (NW4 - 1);
        src = which == 0 ? wq : which == 1 ? wk : which == 2 ? wv : wo;
        dst = which == 0 ? wqkv : which == 1 ? wqkv + DM * DM : which == 2 ? wqkv + 2 * DM * DM : wob;
      }
      float4 v = ((const float4*)src)[off];
      bf16x4 o4 = { (bf16)v.x, (bf16)v.y, (bf16)v.z, (bf16)v.w };
      ((bf16x4*)dst)[off] = o4;
    } else {
      int e = i - TOTC;
      int s = e >> 5, p = e & 31;
      float invf = __builtin_exp2f(-(float)p * (13.287712379549449f / 32.0f));
      float ang = (float)pos[s] * invf;
      fx2 cs; cs.x = cosf(ang); cs.y = sinf(ang);
      tab[e] = cs;
    }
  }
}

// ---- 128x128 bf16 GEMM mainloop, 3-buffer ring + counted vmcnt (T3+T4).
DEV void gemm_bt_128(const bf16* __restrict__ A, const bf16* __restrict__ Bw,
                     int rowA0, int rowB0, f32x4 (&acc)[4][4], bf16* lds) {
  const int t = threadIdx.x, w = t >> 6, lane = t & 63;
  const int wr = w >> 1, wc = w & 1, g = lane >> 4, c = lane & 15;
#pragma unroll
  for (int mi = 0; mi < 4; mi++)
#pragma unroll
    for (int ni = 0; ni < 4; ni++) acc[mi][ni] = (f32x4){0.f, 0.f, 0.f, 0.f};
  const bf16* ga = A + (size_t)(rowA0 + (t >> 2)) * DM + (t & 3) * 8;
  const bf16* gb = Bw + (size_t)(rowB0 + (t >> 2)) * DM + (t & 3) * 8;
  const int arow = wr * 64 + c, brow = wc * 64 + c;
  auto stage = [&](int k0, int buf) {
    bf16* la = lds + buf * 8192 + w * 512;        // wave-uniform base
    bf16* lb = lds + buf * 8192 + 4096 + w * 512;
    gload16(ga + k0,            la);
    gload16(ga + k0 + 64 * DM,  la + 2048);
    gload16(gb + k0,            lb);
    gload16(gb + k0 + 64 * DM,  lb + 2048);
  };
  stage(0, 0);
  stage(32, 1);
  asm volatile("s_waitcnt vmcnt(4)" ::: "memory");   // tile 0 landed (mine)
  __builtin_amdgcn_s_barrier();                      // cross-wave: tile 0 ready
  __builtin_amdgcn_sched_barrier(0);
  for (int it = 0; it < 32; ++it) {
    const int cur = it % 3;
    const bf16* lA = lds + cur * 8192;
    const bf16* lB = lds + cur * 8192 + 4096;
    bf16x8 af[4], bf_[4];
#pragma unroll
    for (int mi = 0; mi < 4; mi++) af[mi]  = *(const bf16x8*)(lA + (arow + mi * 16) * 32 + g * 8);
#pragma unroll
    for (int ni = 0; ni < 4; ni++) bf_[ni] = *(const bf16x8*)(lB + (brow + ni * 16) * 32 + g * 8);
#pragma unroll
    for (int mi = 0; mi < 4; mi++)
#pragma unroll
      for (int ni = 0; ni < 4; ni++)
        acc[mi][ni] = mfma16(af[mi], bf_[ni], acc[mi][ni]);
    // stage tile t+2 into buf (t+2)%3 (last read at iter t-1, fenced by its barrier)
    if (it + 2 < 32) stage((it + 2) * 32, (it + 2) % 3);
    if (it + 1 < 32) {
      if (it + 2 < 32) asm volatile("s_waitcnt vmcnt(4)" ::: "memory");  // t+1 landed
      else             asm volatile("s_waitcnt vmcnt(0)" ::: "memory");  // final tile
      __builtin_amdgcn_s_barrier();
      __builtin_amdgcn_sched_barrier(0);
    }
  }
}

// ---------------- QKV projection + RoPE epilogue (LDS re-layout, coalesced out) ----
__global__ __launch_bounds__(256, 3) void qkv_kernel(const bf16* __restrict__ xb,
    const bf16* __restrict__ wqkv, const fx2* __restrict__ tab,
    bf16* __restrict__ Qb, bf16* __restrict__ KFb, bf16* __restrict__ VFb) {
  __shared__ __align__(16) bf16 L[24576];            // 48KB: 3-buf gemm ring
  f32x4 acc[4][4];
  const int rowA0 = blockIdx.y * 128, rowB0 = blockIdx.x * 128;
  gemm_bt_128(xb, wqkv, rowA0, rowB0, acc, L);
  const int t = threadIdx.x, w = t >> 6, lane = t & 63;
  const int wr = w >> 1, wc = w & 1, g = lane >> 4, c = lane & 15;
  const int which = rowB0 >> 10;
  const int b = rowA0 >> 11;
  const int s0 = rowA0 & (SS - 1);
  const int h0 = (rowB0 & (DM - 1)) >> 6;
  const int kt0 = s0 >> 6;
  // last gemm iter reads only buf2; epilogue uses lds[0..16383] -> disjoint.
#pragma unroll
  for (int mi = 0; mi < 4; mi++)
#pragma unroll
    for (int ni = 0; ni < 4; ni++) {
      const int col = wc * 64 + ni * 16 + c;      // 0..127
      const int hh = col >> 6, dd = col & 63;
#pragma unroll
      for (int j = 0; j < 4; j++) {
        const int sp = wr * 64 + mi * 16 + 4 * g + j;   // 0..127
        float v = acc[mi][ni][j];
        int flat;
        if (which < 2) {
          const int s = s0 + sp;
          float partner = __shfl_xor(v, 1);
          fx2 cs = tab[s * 32 + (dd >> 1)];
          v = v * cs.x + ((dd & 1) ? partner : -partner) * cs.y;
          if (which == 0) {
            flat = hh * 8192 + sp * 64 + dd;
          } else {
            const int spp = sp & 63;
            flat = (hh * 2 + (sp >> 6)) * 4096 +
                   (((spp >> 5) * 4 + (dd >> 4)) * 64 + (spp & 31) + 32 * ((dd >> 3) & 1)) * 8 +
                   (dd & 7);
          }
        } else {
          const int spp = sp & 63;   // = mi*16 + 4g + j
          flat = (hh * 2 + (sp >> 6)) * 4096 +
                 (((dd >> 5) * 4 + mi) * 64 + (dd & 31) + 32 * (g >> 1)) * 8 + (spp & 7);
        }
        L[flat] = (bf16)v;
      }
    }
  __syncthreads();
  if (which == 0) {
    bf16* base0 = Qb + ((size_t)(b * NH + h0) * SS + s0) * HD;
    bf16* base1 = Qb + ((size_t)(b * NH + h0 + 1) * SS + s0) * HD;
#pragma unroll
    for (int j2 = 0; j2 < 8; j2++) {
      const int off = j2 * 2048 + t * 8;
      bf16* dst = (off < 8192 ? base0 : base1) + (off & 8191);
      *(bf16x8*)dst = *(const bf16x8*)(L + off);
    }
  } else {
    bf16* outp = (which == 1) ? KFb : VFb;
#pragma unroll
    for (int j2 = 0; j2 < 8; j2++) {
      const int off = j2 * 2048 + t * 8;
      const int r = off >> 12;                 // 0..3 = h'*2 + kt'
      bf16* dst = outp + ((size_t)(b * NH + h0 + (r >> 1)) * 32 + kt0 + (r & 1)) * 4096 + (off & 4095);
      *(bf16x8*)dst = *(const bf16x8*)(L + off);
    }
  }
}

// ---------------- flash attention (causal), dual-chunk ILP across batch ----------------
// 512 blocks (16 h x 32 ci-pairs) x 256 thr, launch_bounds(256,2): ALL blocks
// resident (2/CU), uniform work. Block handles chunk ci for BOTH batches
// (chunk A = b0, chunk B = b1: identical nt/mask -> two independent dep chains
// per wave; MFMA and VALU pipes co-issue), then chunk 63-ci for both batches
// (uniform 33-34 dual-visits). Visit body = R20 verbatim, A/B suffixed.
// 4-wave split-k per chunk with LDS merge (duplicated for A and B).
__global__ __launch_bounds__(256, 2) void attn_kernel(const bf16* __restrict__ Q,
    const bf16* __restrict__ KF, const bf16* __restrict__ VF, bf16* __restrict__ AO) {
  __shared__ float OmA[3][2048], OmB[3][2048];
  __shared__ float MlA[3][32], LlA[3][32], MlB[3][32], LlB[3][32];
  const int flat = blockIdx.x;                       // 0..511
  const int flat2 = (flat & 7) * 64 + (flat >> 3);   // XCD-contiguous
  const int h = flat2 >> 5;                          // 0..15 (2 heads per XCD)
  const int pi = flat2 & 31;                         // ci-pair index
  const int w = threadIdx.x >> 6;                    // wave 0..3
  const int lane = threadIdx.x & 63;
  const int q31 = lane & 31, hi = lane >> 5;
  const int bh0 = h, bh1 = NH + h;                   // b=0 / b=1, same head
  const bf16* QpA = Q + (size_t)bh0 * SS * HD;
  const bf16* QpB = Q + (size_t)bh1 * SS * HD;
  const bf16* KFpA = KF + (size_t)bh0 * SS * HD;
  const bf16* KFpB = KF + (size_t)bh1 * SS * HD;
  const bf16* VFpA = VF + (size_t)bh0 * SS * HD;
  const bf16* VFpB = VF + (size_t)bh1 * SS * HD;
  const float SCL = 0.125f * LOG2E;                  // exp2-domain scale

  auto run_dual = [&](int ci) {
    const int qbase = ci * 32;
    const int nt = ci / 2 + 1;
    // Q frags (B-operand) for both chunks, scaled
    bf16x8 qbA[4], qbB[4];
#pragma unroll
    for (int ds = 0; ds < 4; ds++) {
      bf16x8 xa = *(const bf16x8*)(QpA + (size_t)(qbase + q31) * HD + ds * 16 + hi * 8);
      bf16x8 xb2 = *(const bf16x8*)(QpB + (size_t)(qbase + q31) * HD + ds * 16 + hi * 8);
#pragma unroll
      for (int e = 0; e < 8; e++) {
        xa[e]  = (bf16)((float)xa[e]  * SCL);
        xb2[e] = (bf16)((float)xb2[e] * SCL);
      }
      qbA[ds] = xa; qbB[ds] = xb2;
    }
    float mA = -3.0e38f, lA = 0.f, mB = -3.0e38f, lB = 0.f;
    f32x16 oA0, oA1, oB0, oB1;
#pragma unroll
    for (int e = 0; e < 16; e++) { oA0[e] = 0.f; oA1[e] = 0.f; oB0[e] = 0.f; oB1[e] = 0.f; }

    for (int tv = w; tv < nt; tv += 4) {
      const int k0 = tv * 64;
      const bf16* ktA = KFpA + (size_t)tv * 4096;
      const bf16* ktB = KFpB + (size_t)tv * 4096;
      const bf16* vtA = VFpA + (size_t)tv * 4096;
      const bf16* vtB = VFpB + (size_t)tv * 4096;
      const bool diag = (k0 + 63 > qbase);
      const int qg = qbase + q31;
      // ---- QK^T chunk A ----
      f32x16 sA0, sA1;
#pragma unroll
      for (int e = 0; e < 16; e++) { sA0[e] = 0.f; sA1[e] = 0.f; }
      {
        bf16x8 kf[4];
#pragma unroll
        for (int ds = 0; ds < 4; ds++)
          kf[ds] = *(const bf16x8*)(ktA + (size_t)(ds * 64 + lane) * 8);
#pragma unroll
        for (int ds = 0; ds < 4; ds++) sA0 = mfma32(kf[ds], qbA[ds], sA0);
#pragma unroll
        for (int ds = 0; ds < 4; ds++)
          kf[ds] = *(const bf16x8*)(ktA + (size_t)((4 + ds) * 64 + lane) * 8);
#pragma unroll
        for (int ds = 0; ds < 4; ds++) sA1 = mfma32(kf[ds], qbA[ds], sA1);
      }
      // ---- QK^T chunk B (independent chain; overlaps A's softmax below) ----
      f32x16 sB0, sB1;
#pragma unroll
      for (int e = 0; e < 16; e++) { sB0[e] = 0.f; sB1[e] = 0.f; }
      {
        bf16x8 kf[4];
#pragma unroll
        for (int ds = 0; ds < 4; ds++)
          kf[ds] = *(const bf16x8*)(ktB + (size_t)(ds * 64 + lane) * 8);
#pragma unroll
        for (int ds = 0; ds < 4; ds++) sB0 = mfma32(kf[ds], qbB[ds], sB0);
#pragma unroll
        for (int ds = 0; ds < 4; ds++)
          kf[ds] = *(const bf16x8*)(ktB + (size_t)((4 + ds) * 64 + lane) * 8);
#pragma unroll
        for (int ds = 0; ds < 4; ds++) sB1 = mfma32(kf[ds], qbB[ds], sB1);
      }
      // ---- masks (shared geometry) ----
      if (diag) {
#pragma unroll
        for (int r = 0; r < 16; r++) {
          const int kg = k0 + (r & 3) + 8 * (r >> 2) + 4 * hi;
          if (kg > qg)      { sA0[r] = -1.0e30f; sB0[r] = -1.0e30f; }
          if (kg + 32 > qg) { sA1[r] = -1.0e30f; sB1[r] = -1.0e30f; }
        }
      }
      // ---- softmax A (VALU chain; B's MFMA results already in flight) ----
      {
        float a[16];
#pragma unroll
        for (int r = 0; r < 16; r++) a[r] = fmaxf(sA0[r], sA1[r]);
#pragma unroll
        for (int d = 8; d > 0; d >>= 1)
#pragma unroll
          for (int r = 0; r < d; r++) a[r] = fmaxf(a[r], a[r + d]);
        const float pm = fmaxf(a[0], __shfl_xor(a[0], 32));
        if (__any(pm > mA + 8.0f)) {
          const float mnew = fmaxf(mA, pm);
          const float alpha = __builtin_exp2f(mA - mnew);
          lA *= alpha;
#pragma unroll
          for (int e = 0; e < 16; e++) { oA0[e] *= alpha; oA1[e] *= alpha; }
          mA = mnew;
        }
        float b2[16];
#pragma unroll
        for (int r = 0; r < 16; r++) {
          sA0[r] = __builtin_exp2f(sA0[r] - mA);
          sA1[r] = __builtin_exp2f(sA1[r] - mA);
          b2[r] = sA0[r] + sA1[r];
        }
#pragma unroll
        for (int d = 8; d > 0; d >>= 1)
#pragma unroll
          for (int r = 0; r < d; r++) b2[r] += b2[r + d];
        lA += b2[0] + __shfl_xor(b2[0], 32);
      }
      // ---- pack A + PV A (MFMA; overlaps B's softmax below) ----
      bf16x8 pfA[4];
#pragma unroll
      for (int ks = 0; ks < 4; ks++) {
        const int rb = 8 * (ks & 1);
        float va0, va1, va2, va3, vb0, vb1, vb2, vb3;
        if (ks < 2) {
          va0 = sA0[rb]; va1 = sA0[rb + 1]; va2 = sA0[rb + 2]; va3 = sA0[rb + 3];
          vb0 = sA0[rb + 4]; vb1 = sA0[rb + 5]; vb2 = sA0[rb + 6]; vb3 = sA0[rb + 7];
        } else {
          va0 = sA1[rb]; va1 = sA1[rb + 1]; va2 = sA1[rb + 2]; va3 = sA1[rb + 3];
          vb0 = sA1[rb + 4]; vb1 = sA1[rb + 5]; vb2 = sA1[rb + 6]; vb3 = sA1[rb + 7];
        }
        const unsigned a01 = pack2(va0, va1), a23 = pack2(va2, va3);
        const unsigned b01 = pack2(vb0, vb1), b23 = pack2(vb2, vb3);
        const unsigned z1 = (unsigned)__shfl_xor((int)(hi ? a01 : b01), 32);
        const unsigned z2 = (unsigned)__shfl_xor((int)(hi ? a23 : b23), 32);
        union { unsigned u[4]; bf16x8 v; } cv;
        cv.u[0] = hi ? z1 : a01;
        cv.u[1] = hi ? z2 : a23;
        cv.u[2] = hi ? b01 : z1;
        cv.u[3] = hi ? b23 : z2;
        pfA[ks] = cv.v;
      }
      {
        bf16x8 vf[4];
#pragma unroll
        for (int ks = 0; ks < 4; ks++)
          vf[ks] = *(const bf16x8*)(vtA + (size_t)(ks * 64 + lane) * 8);
#pragma unroll
        for (int ks = 0; ks < 4; ks++) oA0 = mfma32(vf[ks], pfA[ks], oA0);
#pragma unroll
        for (int ks = 0; ks < 4; ks++)
          vf[ks] = *(const bf16x8*)(vtA + (size_t)((4 + ks) * 64 + lane) * 8);
#pragma unroll
        for (int ks = 0; ks < 4; ks++) oA1 = mfma32(vf[ks], pfA[ks], oA1);
      }
      // ---- softmax B ----
      {
        float a[16];
#pragma unroll
        for (int r = 0; r < 16; r++) a[r] = fmaxf(sB0[r], sB1[r]);
#pragma unroll
        for (int d = 8; d > 0; d >>= 1)
#pragma unroll
          for (int r = 0; r < d; r++) a[r] = fmaxf(a[r], a[r + d]);
        const float pm = fmaxf(a[0], __shfl_xor(a[0], 32));
        if (__any(pm > mB + 8.0f)) {
          const float mnew = fmaxf(mB, pm);
          const float alpha = __builtin_exp2f(mB - mnew);
          lB *= alpha;
#pragma unroll
          for (int e = 0; e < 16; e++) { oB0[e] *= alpha; oB1[e] *= alpha; }
          mB = mnew;
        }
        float b2[16];
#pragma unroll
        for (int r = 0; r < 16; r++) {
          sB0[r] = __builtin_exp2f(sB0[r] - mB);
          sB1[r] = __builtin_exp2f(sB1[r] - mB);
          b2[r] = sB0[r] + sB1[r];
        }
#pragma unroll
        for (int d = 8; d > 0; d >>= 1)
#pragma unroll
          for (int r = 0; r < d; r++) b2[r] += b2[r + d];
        lB += b2[0] + __shfl_xor(b2[0], 32);
      }
      // ---- pack B + PV B ----
      bf16x8 pfB[4];
#pragma unroll
      for (int ks = 0; ks < 4; ks++) {
        const int rb = 8 * (ks & 1);
        float va0, va1, va2, va3, vb0, vb1, vb2, vb3;
        if (ks < 2) {
          va0 = sB0[rb]; va1 = sB0[rb + 1]; va2 = sB0[rb + 2]; va3 = sB0[rb + 3];
          vb0 = sB0[rb + 4]; vb1 = sB0[rb + 5]; vb2 = sB0[rb + 6]; vb3 = sB0[rb + 7];
        } else {
          va0 = sB1[rb]; va1 = sB1[rb + 1]; va2 = sB1[rb + 2]; va3 = sB1[rb + 3];
          vb0 = sB1[rb + 4]; vb1 = sB1[rb + 5]; vb2 = sB1[rb + 6]; vb3 = sB1[rb + 7];
        }
        const unsigned a01 = pack2(va0, va1), a23 = pack2(va2, va3);
        const unsigned b01 = pack2(vb0, vb1), b23 = pack2(vb2, vb3);
        const unsigned z1 = (unsigned)__shfl_xor((int)(hi ? a01 : b01), 32);
        const unsigned z2 = (unsigned)__shfl_xor((int)(hi ? a23 : b23), 32);
        union { unsigned u[4]; bf16x8 v; } cv;
        cv.u[0] = hi ? z1 : a01;
        cv.u[1] = hi ? z2 : a23;
        cv.u[2] = hi ? b01 : z1;
        cv.u[3] = hi ? b23 : z2;
        pfB[ks] = cv.v;
      }
      {
        bf16x8 vf[4];
#pragma unroll
        for (int ks = 0; ks < 4; ks++)
          vf[ks] = *(const bf16x8*)(vtB + (size_t)(ks * 64 + lane) * 8);
#pragma unroll
        for (int ks = 0; ks < 4; ks++) oB0 = mfma32(vf[ks], pfB[ks], oB0);
#pragma unroll
        for (int ks = 0; ks < 4; ks++)
          vf[ks] = *(const bf16x8*)(vtB + (size_t)((4 + ks) * 64 + lane) * 8);
#pragma unroll
        for (int ks = 0; ks < 4; ks++) oB1 = mfma32(vf[ks], pfB[ks], oB1);
      }
    }
    // ---- publish partials (waves 1..3), merge + store (wave 0), both chunks ----
    __syncthreads();
    if (w) {
#pragma unroll
      for (int e = 0; e < 16; e++) {
        const int r = (e & 3) + 8 * (e >> 2) + 4 * hi;
        OmA[w - 1][r * 32 + q31] = oA0[e];
        OmA[w - 1][(r + 32) * 32 + q31] = oA1[e];
        OmB[w - 1][r * 32 + q31] = oB0[e];
        OmB[w - 1][(r + 32) * 32 + q31] = oB1[e];
      }
      if (!hi) {
        MlA[w - 1][q31] = mA; LlA[w - 1][q31] = lA;
        MlB[w - 1][q31] = mB; LlB[w - 1][q31] = lB;
      }
    }
    __syncthreads();
    if (!w) {
      // merge+store chunk A (b=0) then chunk B (b=1)
#pragma unroll
      for (int cb = 0; cb < 2; cb++) {
        float (*Om)[2048] = cb ? OmB : OmA;
        float (*Ml)[32] = cb ? MlB : MlA;
        float (*Ll)[32] = cb ? LlB : LlA;
        const float mS = cb ? mB : mA;
        const float lS = cb ? lB : lA;
        f32x16& p0 = cb ? oB0 : oA0;
        f32x16& p1 = cb ? oB1 : oA1;
        float mi_[3];
#pragma unroll
        for (int i = 0; i < 3; i++) mi_[i] = Ml[i][q31];
        float mm = fmaxf(fmaxf(mS, mi_[0]), fmaxf(mi_[1], mi_[2]));
        const float aS = __builtin_exp2f(mS - mm);
        float ai[3];
        float L2 = aS * lS;
#pragma unroll
        for (int i = 0; i < 3; i++) {
          ai[i] = __builtin_exp2f(mi_[i] - mm);
          L2 += ai[i] * Ll[i][q31];
        }
        const float linv = 1.0f / L2;
        const size_t rowb = ((size_t)(cb * SS + qbase + q31)) * DM + h * HD;
#pragma unroll
        for (int g2 = 0; g2 < 4; g2++) {
          bf16x4 w0v, w1v;
#pragma unroll
          for (int j = 0; j < 4; j++) {
            const int e = 4 * g2 + j;
            const int r = j + 8 * g2 + 4 * hi;
            float v0 = aS * p0[e];
            float v1 = aS * p1[e];
#pragma unroll
            for (int i = 0; i < 3; i++) {
              v0 += ai[i] * Om[i][r * 32 + q31];
              v1 += ai[i] * Om[i][(r + 32) * 32 + q31];
            }
            w0v[j] = (bf16)(v0 * linv);
            w1v[j] = (bf16)(v1 * linv);
          }
          *(bf16x4*)(AO + rowb +      8 * g2 + 4 * hi) = w0v;
          *(bf16x4*)(AO + rowb + 32 + 8 * g2 + 4 * hi) = w1v;
        }
      }
    }
    __syncthreads();   // protect merge buffers before next phase's publishes
  };

  // phase 1: chunk ci = 63-pi (long); phase 2: chunk ci = pi (short). Uniform
  // total of 33-34 dual-visits per block; all 512 blocks fully resident.
  run_dual(63 - pi);
  run_dual(pi);
}

// ---------------- output projection -> fp32 d_out ----------------
__global__ __launch_bounds__(256, 2) void oproj_kernel(const bf16* __restrict__ AO,
    const bf16* __restrict__ wob, float* __restrict__ out) {
  __shared__ __align__(16) bf16 L[24576];
  f32x4 acc[4][4];
  const int rowA0 = blockIdx.y * 128, rowB0 = blockIdx.x * 128;
  gemm_bt_128(AO, wob, rowA0, rowB0, acc, L);
  const int t = threadIdx.x, w = t >> 6, lane = t & 63;
  const int wr = w >> 1, wc = w & 1, g = lane >> 4, c = lane & 15;
#pragma unroll
  for (int mi = 0; mi < 4; mi++)
#pragma unroll
    for (int ni = 0; ni < 4; ni++) {
      const int ncol = rowB0 + wc * 64 + ni * 16 + c;
#pragma unroll
      for (int j = 0; j < 4; j++) {
        const int mrow = rowA0 + wr * 64 + mi * 16 + 4 * g + j;
        out[(size_t)mrow * DM + ncol] = acc[mi][ni][j];
      }
    }
}

extern "C" void kernel_launch(void* const* d_in, const int* in_sizes, int n_in,
                              void* d_out, int out_size, void* d_ws, size_t ws_size,
                              hipStream_t stream) {
  const float* x  = (const float*)d_in[0];
  const float* wq = (const float*)d_in[1];
  const float* wk = (const float*)d_in[2];
  const float* wv = (const float*)d_in[3];
  const float* wo = (const float*)d_in[4];
  const int*   pos = (const int*)d_in[5];
  char* ws = (char*)d_ws;
  bf16* xb   = (bf16*)(ws + OFF_XB);
  bf16* wqkv = (bf16*)(ws + OFF_WQKV);
  bf16* wob  = (bf16*)(ws + OFF_WO);
  fx2*  tab  = (fx2*)(ws + OFF_TAB);
  bf16* Qb   = (bf16*)(ws + OFF_Q);
  bf16* KFb  = (bf16*)(ws + OFF_KF);
  bf16* VFb  = (bf16*)(ws + OFF_VF);
  bf16* AOb  = (bf16*)(ws + OFF_AO);

  hipLaunchKernelGGL(prep_kernel, dim3(2048), dim3(256), 0, stream,
                     x, wq, wk, wv, wo, pos, xb, wqkv, wob, tab);
  hipLaunchKernelGGL(qkv_kernel, dim3(24, 32), dim3(256), 0, stream,
                     xb, wqkv, tab, Qb, KFb, VFb);
  hipLaunchKernelGGL(attn_kernel, dim3(512), dim3(256), 0, stream,
                     Qb, KFb, VFb, AOb);
  hipLaunchKernelGGL(oproj_kernel, dim3(8, 32), dim3(256), 0, stream,
                     AOb, wob, (float*)d_out);
}